// Round 4
// baseline (277.856 us; speedup 1.0000x reference)
//
#include <hip/hip_runtime.h>
#include <hip/hip_cooperative_groups.h>
#include <math.h>

namespace cg = cooperative_groups;

// BoundaryDistanceLoss — H=W=1024 binary masks (float 0/1).
// edges = seg - erode3x3(seg); exact EDT of edges; loss =
// sigmoid((mean(target_edges*pred_dt) + mean(pred_edges*target_dt))/2).
//
// R3->R4: fused all 3 kernels into ONE cooperative kernel (grid.sync between
// phases) to kill per-node drain/launch overhead (~20 us of the 78).
// Numeric path identical to R3 (absmax 0.0).
//
// ws layout: hp (4MB) | ht (4MB) | ep (1MB u8) | et (1MB u8) | partial (4KB)
// h[k][j] = g2[k][j] + k^2   (g2 = squared row-pass distance)

#define HW 1024
#define BIGF 1e6f
#define RMIN_SENT (1 << 30)
#define WIN 8
#define RPB 128
#define KROWS (RPB + 2 * WIN)   // 144
#define HS_STRIDE 17
#define GRID 512                // 2 blocks/CU — co-residency trivially satisfied

__global__ __launch_bounds__(256, 2)
void k_fused(const float* __restrict__ pred, const float* __restrict__ targ,
             float* __restrict__ hp, float* __restrict__ ht,
             unsigned char* __restrict__ ep, unsigned char* __restrict__ et,
             float* __restrict__ partial, float* __restrict__ out)
{
    __shared__ unsigned char colall[HW];
    __shared__ int wtotL[4];
    __shared__ int wtotR[4];
    __shared__ float hs[KROWS * HS_STRIDE];
    __shared__ alignas(16) unsigned char es[RPB * 16];
    __shared__ float wsum[4];

    const int t = threadIdx.x;
    cg::grid_group grid = cg::this_grid();

    // ================= Phase 1: edges + row-pass (4 rows per block) =========
    for (int task = blockIdx.x; task < 2 * HW; task += GRID) {
        const int r = task & (HW - 1);
        const int m = task >> 10;
        const float* __restrict__ seg = m ? targ : pred;
        float* __restrict__ hout = m ? ht : hp;
        unsigned char* __restrict__ eout = m ? et : ep;

        const int j4 = t * 4;
        float4 c0 = *(const float4*)&seg[r * HW + j4];
        float4 cm = make_float4(0.f, 0.f, 0.f, 0.f);
        float4 cp = make_float4(0.f, 0.f, 0.f, 0.f);
        if (r > 0)        cm = *(const float4*)&seg[(r - 1) * HW + j4];
        if (r < HW - 1)   cp = *(const float4*)&seg[(r + 1) * HW + j4];

        const float s0v[4] = {c0.x, c0.y, c0.z, c0.w};
        const float smv[4] = {cm.x, cm.y, cm.z, cm.w};
        const float spv[4] = {cp.x, cp.y, cp.z, cp.w};

        unsigned char ca[4];
        #pragma unroll
        for (int u = 0; u < 4; ++u)
            ca[u] = (s0v[u] != 0.f && smv[u] != 0.f && spv[u] != 0.f) ? 1 : 0;
        *(uchar4*)&colall[j4] = make_uchar4(ca[0], ca[1], ca[2], ca[3]);
        __syncthreads();   // barrier 1 (also protects colall across iterations)

        int lmax = -1, rmin = RMIN_SENT;
        unsigned char fe[4];
        #pragma unroll
        for (int u = 0; u < 4; ++u) {
            const int j = j4 + u;
            int er = 0;
            if (j > 0 && j < HW - 1)
                er = colall[j - 1] & ca[u] & colall[j + 1];
            const int e = (s0v[u] != 0.f) && !er;
            fe[u] = (unsigned char)e;
            if (e) { lmax = j; if (rmin == RMIN_SENT) rmin = j; }
        }
        *(uchar4*)&eout[r * HW + j4] = make_uchar4(fe[0], fe[1], fe[2], fe[3]);

        // intra-wave inclusive scans via shuffles (no barriers)
        const int lane = t & 63;
        const int wv   = t >> 6;
        int Li = lmax;
        #pragma unroll
        for (int off = 1; off < 64; off <<= 1) {
            const int v = __shfl_up(Li, off);
            if (lane >= off) Li = max(Li, v);
        }
        int Ri = rmin;
        #pragma unroll
        for (int off = 1; off < 64; off <<= 1) {
            const int v = __shfl_down(Ri, off);
            if (lane + off < 64) Ri = min(Ri, v);
        }
        if (lane == 63) wtotL[wv] = Li;
        if (lane == 0)  wtotR[wv] = Ri;
        int exL = __shfl_up(Li, 1);   if (lane == 0)  exL = -1;
        int exR = __shfl_down(Ri, 1); if (lane == 63) exR = RMIN_SENT;
        __syncthreads();   // barrier 2
        int baseL = -1, baseR = RMIN_SENT;
        #pragma unroll
        for (int w2 = 0; w2 < 4; ++w2) {
            if (w2 < wv) baseL = max(baseL, wtotL[w2]);
            if (w2 > wv) baseR = min(baseR, wtotR[w2]);
        }
        const int carryL = max(baseL, exL);
        const int carryR = min(baseR, exR);

        int Lv[4], Rv[4];
        {
            int L = carryL;
            #pragma unroll
            for (int u = 0; u < 4; ++u) { if (fe[u]) L = j4 + u; Lv[u] = L; }
        }
        {
            int R = carryR;
            #pragma unroll
            for (int u = 3; u >= 0; --u) { if (fe[u]) R = j4 + u; Rv[u] = R; }
        }

        const float rr = (float)(r * r);
        float hv[4];
        #pragma unroll
        for (int u = 0; u < 4; ++u) {
            const float jf = (float)(j4 + u);
            const float left  = jf - ((Lv[u] < 0) ? -BIGF : (float)Lv[u]);
            const float right = ((Rv[u] >= RMIN_SENT) ? BIGF : (float)Rv[u]) - jf;
            float g = fminf(fminf(left, right), BIGF);
            hv[u] = g * g + rr;
        }
        float4 ho; ho.x = hv[0]; ho.y = hv[1]; ho.z = hv[2]; ho.w = hv[3];
        *(float4*)&hout[r * HW + j4] = ho;
    }

    __threadfence();
    grid.sync();

    // ================= Phase 2: column EDT (windowed, exact) ================
    for (int task = blockIdx.x; task < 1024; task += GRID) {
        const int jt = task & 63;
        const int it = (task >> 6) & 7;
        const int m  = task >> 9;
        const int j0 = jt * 16;
        const int i0 = it * RPB;
        const float* __restrict__ hg = m ? ht : hp;
        const unsigned char* __restrict__ ew = m ? ep : et;  // OTHER image's edges

        for (int idx = t; idx < KROWS * 16; idx += 256) {
            const int kk = idx >> 4, jc = idx & 15;
            const int gk = i0 - WIN + kk;
            float v = 1e30f;
            if ((unsigned)gk < (unsigned)HW) v = hg[gk * HW + j0 + jc];
            hs[kk * HS_STRIDE + jc] = v;
        }
        if (t < RPB)
            *(uint4*)&es[t * 16] = *(const uint4*)&ew[(i0 + t) * HW + j0];
        __syncthreads();

        const int jj = t & 15;
        const int iw = t >> 4;   // 0..15, each owns 8 rows
        float lsum = 0.f;

        #pragma unroll
        for (int g = 0; g < 2; ++g) {
            const int ib = i0 + iw * 8 + g * 4;
            const int kkS = iw * 8 + g * 4;
            float b0 = 3e38f, b1 = 3e38f, b2 = 3e38f, b3 = 3e38f;
            float kf = (float)(ib - WIN);
            const float m0 = -2.f * (float)(ib);
            const float m1 = -2.f * (float)(ib + 1);
            const float m2 = -2.f * (float)(ib + 2);
            const float m3 = -2.f * (float)(ib + 3);
            #pragma unroll
            for (int kk = kkS; kk < kkS + 2 * WIN + 4; ++kk) {
                const float hvv = hs[kk * HS_STRIDE + jj];
                b0 = fminf(b0, fmaf(m0, kf, hvv));
                b1 = fminf(b1, fmaf(m1, kf, hvv));
                b2 = fminf(b2, fmaf(m2, kf, hvv));
                b3 = fminf(b3, fmaf(m3, kf, hvv));
                kf += 1.f;
            }
            const int sLo = max(0, ib - WIN);
            const int sHi = min(HW - 1, ib + WIN + 3);
            float bs[4] = {b0, b1, b2, b3};
            #pragma unroll
            for (int w = 0; w < 4; ++w) {
                const int i = ib + w;
                float D2 = (float)(i * i) + bs[w];
                const int dl = i - sLo + 1, dr = sHi + 1 - i;
                const bool need = ((sLo > 0) && (D2 > (float)(dl * dl))) ||
                                  ((sHi < HW - 1) && (D2 > (float)(dr * dr)));
                if (need) {  // statistically-dead exact fallback
                    float bb = 3e38f, k2 = 0.f;
                    const float mm = -2.f * (float)i;
                    for (int k = 0; k < HW; ++k) {
                        bb = fminf(bb, fmaf(mm, k2, hg[k * HW + j0 + jj]));
                        k2 += 1.f;
                    }
                    D2 = (float)(i * i) + bb;
                }
                const float wgt = (float)es[(i - i0) * 16 + jj];
                lsum = fmaf(wgt, sqrtf(D2), lsum);
            }
        }

        #pragma unroll
        for (int off = 32; off > 0; off >>= 1) lsum += __shfl_down(lsum, off);
        if ((t & 63) == 0) wsum[t >> 6] = lsum;
        __syncthreads();
        if (t == 0)
            partial[task] = wsum[0] + wsum[1] + wsum[2] + wsum[3];
        __syncthreads();   // protect hs/es/wsum before next task iteration
    }

    __threadfence();
    grid.sync();

    // ================= Phase 3: reduce 1024 partials + sigmoid ==============
    if (blockIdx.x == 0) {
        float s = partial[t] + partial[t + 256] + partial[t + 512] + partial[t + 768];
        #pragma unroll
        for (int off = 32; off > 0; off >>= 1) s += __shfl_down(s, off);
        if ((t & 63) == 0) wsum[t >> 6] = s;
        __syncthreads();
        if (t == 0) {
            const float tot = wsum[0] + wsum[1] + wsum[2] + wsum[3];
            const float loss = tot * (1.f / (2.f * 1024.f * 1024.f));
            out[0] = 1.f / (1.f + expf(-loss));
        }
    }
}

extern "C" void kernel_launch(void* const* d_in, const int* in_sizes, int n_in,
                              void* d_out, int out_size, void* d_ws, size_t ws_size,
                              hipStream_t stream)
{
    const float* preds   = (const float*)d_in[0];
    const float* targets = (const float*)d_in[1];
    float* out = (float*)d_out;

    char* ws = (char*)d_ws;
    float* hp = (float*)ws;                               // 4 MB
    float* ht = hp + HW * HW;                             // 4 MB
    unsigned char* ep = (unsigned char*)(ht + HW * HW);   // 1 MB
    unsigned char* et = ep + HW * HW;                     // 1 MB
    float* partial = (float*)(et + HW * HW);              // 4 KB

    void* args[] = { (void*)&preds, (void*)&targets, (void*)&hp, (void*)&ht,
                     (void*)&ep, (void*)&et, (void*)&partial, (void*)&out };
    hipLaunchCooperativeKernel((const void*)k_fused, dim3(GRID), dim3(256),
                               args, 0, stream);
}

// Round 5
// 77.129 us; speedup vs baseline: 3.6025x; 3.6025x over previous
//
#include <hip/hip_runtime.h>
#include <math.h>

// BoundaryDistanceLoss — H=W=1024 binary masks (float 0/1).
// edges = seg - erode3x3(seg); exact EDT of edges; loss =
// sigmoid((mean(target_edges*pred_dt) + mean(pred_edges*target_dt))/2).
//
// R4->R5: cooperative fusion reverted (grid.sync measured ~100us/sync on this
// stack: k_fused 210us @ 3.2% VALUBusy). Back to R3's 3-node structure with a
// rebuilt k_rows: one ROW per WAVE, zero barriers/LDS — erosion via 18-bit
// register bitmask window, nearest-feature via __clz/__ffs + 6-step wave scan.
//
// ws layout: hp (4MB) | ht (4MB) | ep (1MB u8) | et (1MB u8) | partial (4KB)
// h[k][j] = g2[k][j] + k^2   (g2 = squared row-pass distance)

#define HW 1024
#define BIGF 1e6f
#define RMIN_SENT (1 << 30)

// ---------------- Kernel A: edges + row-pass (one row per wave) ----------------
// grid (256, 2), block 256 = 4 waves = 4 rows. Lane owns 16 contiguous cols.
__global__ __launch_bounds__(256)
void k_rows(const float* __restrict__ pred, const float* __restrict__ targ,
            float* __restrict__ hp, float* __restrict__ ht,
            unsigned char* __restrict__ ep, unsigned char* __restrict__ et)
{
    const int t    = threadIdx.x;
    const int lane = t & 63;
    const int wv   = t >> 6;
    const int r    = blockIdx.x * 4 + wv;     // row 0..1023
    const int m    = blockIdx.y;              // image 0=pred 1=target
    const float* __restrict__ seg = m ? targ : pred;
    float* __restrict__ hout = m ? ht : hp;
    unsigned char* __restrict__ eout = m ? et : ep;

    const int c0 = lane * 16;                 // first global col of this lane

    float cs[16], cm[16], cp[16];
    #pragma unroll
    for (int q = 0; q < 4; ++q)
        *(float4*)&cs[q * 4] = *(const float4*)&seg[r * HW + c0 + q * 4];
    #pragma unroll
    for (int q = 0; q < 4; ++q) {
        *(float4*)&cm[q * 4] = make_float4(0.f, 0.f, 0.f, 0.f);
        *(float4*)&cp[q * 4] = make_float4(0.f, 0.f, 0.f, 0.f);
    }
    if (r > 0) {
        #pragma unroll
        for (int q = 0; q < 4; ++q)
            *(float4*)&cm[q * 4] = *(const float4*)&seg[(r - 1) * HW + c0 + q * 4];
    }
    if (r < HW - 1) {
        #pragma unroll
        for (int q = 0; q < 4; ++q)
            *(float4*)&cp[q * 4] = *(const float4*)&seg[(r + 1) * HW + c0 + q * 4];
    }

    // bitmasks over the lane's 16 columns
    unsigned s_bits = 0, va_bits = 0;
    #pragma unroll
    for (int x = 0; x < 16; ++x) {
        const unsigned s  = (cs[x] != 0.f) ? 1u : 0u;
        const unsigned va = (cs[x] != 0.f && cm[x] != 0.f && cp[x] != 0.f) ? 1u : 0u;
        s_bits  |= s  << x;
        va_bits |= va << x;
    }

    // neighbor bits across lanes (image border -> 0, matches zero padding)
    const unsigned vprev = __shfl_up(va_bits, 1);
    const unsigned vnext = __shfl_down(va_bits, 1);
    const unsigned lbit = (lane == 0)  ? 0u : ((vprev >> 15) & 1u);
    const unsigned rbit = (lane == 63) ? 0u : (vnext & 1u);

    // eroded_x = va_{x-1} & va_x & va_{x+1} via an 18-bit window
    const unsigned w18 = (va_bits << 1) | lbit | (rbit << 17);
    const unsigned eroded = w18 & (w18 >> 1) & (w18 >> 2);
    const unsigned edge = s_bits & ~eroded & 0xFFFFu;

    // store edge bytes (16 B per lane, coalesced uint4)
    uint4 eb;
    unsigned ew[4];
    #pragma unroll
    for (int q = 0; q < 4; ++q) {
        unsigned u = 0;
        #pragma unroll
        for (int b = 0; b < 4; ++b)
            u |= ((edge >> (q * 4 + b)) & 1u) << (8 * b);
        ew[q] = u;
    }
    eb.x = ew[0]; eb.y = ew[1]; eb.z = ew[2]; eb.w = ew[3];
    *(uint4*)&eout[r * HW + c0] = eb;

    // lane aggregates: last/first set feature col in this lane
    const int lane_last  = edge ? (c0 + 31 - __clz(edge)) : -1;
    const int lane_first = edge ? (c0 + __ffs(edge) - 1)  : RMIN_SENT;

    // wave scans (inclusive), then exclusive carries
    int Li = lane_last;
    #pragma unroll
    for (int off = 1; off < 64; off <<= 1) {
        const int v = __shfl_up(Li, off);
        if (lane >= off) Li = max(Li, v);
    }
    int Ri = lane_first;
    #pragma unroll
    for (int off = 1; off < 64; off <<= 1) {
        const int v = __shfl_down(Ri, off);
        if (lane + off < 64) Ri = min(Ri, v);
    }
    int carryL = __shfl_up(Li, 1);   if (lane == 0)  carryL = -1;
    int carryR = __shfl_down(Ri, 1); if (lane == 63) carryR = RMIN_SENT;

    // per-column nearest feature + h = g^2 + r^2
    const float rr = (float)(r * r);
    float hv[16];
    #pragma unroll
    for (int x = 0; x < 16; ++x) {
        const unsigned ble = edge & ((2u << x) - 1u);   // bits 0..x
        const int L = ble ? (c0 + 31 - __clz(ble)) : carryL;
        const unsigned bge = edge >> x;                 // bits x..15
        const int R = bge ? (c0 + x + __ffs(bge) - 1) : carryR;
        const float jf = (float)(c0 + x);
        const float left  = jf - ((L < 0) ? -BIGF : (float)L);
        const float right = ((R >= RMIN_SENT) ? BIGF : (float)R) - jf;
        const float g = fminf(fminf(left, right), BIGF);
        hv[x] = g * g + rr;
    }
    #pragma unroll
    for (int q = 0; q < 4; ++q)
        *(float4*)&hout[r * HW + c0 + q * 4] = *(float4*)&hv[q * 4];
}

// ------------- Kernel B: column EDT (windowed, exact) + per-block partial -------
// grid (64 col-tiles, 8 row-chunks, 2 images) = 1024 blocks, block 256.
#define WIN 8
#define RPB 128
#define KROWS (RPB + 2 * WIN)   // 144
#define HS_STRIDE 17

__global__ __launch_bounds__(256)
void k_cols(const float* __restrict__ hp, const float* __restrict__ ht,
            const unsigned char* __restrict__ ep, const unsigned char* __restrict__ et,
            float* __restrict__ partial)
{
    const int j0 = blockIdx.x * 16;
    const int i0 = blockIdx.y * RPB;
    const int m  = blockIdx.z;
    const float* __restrict__ hg = m ? ht : hp;
    const unsigned char* __restrict__ ew = m ? ep : et;  // weight = OTHER image's edges

    __shared__ float hs[KROWS * HS_STRIDE];
    __shared__ alignas(16) unsigned char es[RPB * 16];
    __shared__ float wsum[4];

    for (int idx = threadIdx.x; idx < KROWS * 16; idx += 256) {
        const int kk = idx >> 4, jc = idx & 15;
        const int gk = i0 - WIN + kk;
        float v = 1e30f;
        if ((unsigned)gk < (unsigned)HW) v = hg[gk * HW + j0 + jc];
        hs[kk * HS_STRIDE + jc] = v;
    }
    if (threadIdx.x < RPB)
        *(uint4*)&es[threadIdx.x * 16] = *(const uint4*)&ew[(i0 + threadIdx.x) * HW + j0];
    __syncthreads();

    const int jj = threadIdx.x & 15;
    const int iw = threadIdx.x >> 4;   // 0..15, each owns 8 rows
    float lsum = 0.f;

    #pragma unroll
    for (int g = 0; g < 2; ++g) {
        const int ib = i0 + iw * 8 + g * 4;      // 4 consecutive output rows
        const int kkS = iw * 8 + g * 4;          // = (ib-WIN) - (i0-WIN)
        float b0 = 3e38f, b1 = 3e38f, b2 = 3e38f, b3 = 3e38f;
        float kf = (float)(ib - WIN);
        const float m0 = -2.f * (float)(ib);
        const float m1 = -2.f * (float)(ib + 1);
        const float m2 = -2.f * (float)(ib + 2);
        const float m3 = -2.f * (float)(ib + 3);
        #pragma unroll
        for (int kk = kkS; kk < kkS + 2 * WIN + 4; ++kk) {
            const float hvv = hs[kk * HS_STRIDE + jj];
            b0 = fminf(b0, fmaf(m0, kf, hvv));
            b1 = fminf(b1, fmaf(m1, kf, hvv));
            b2 = fminf(b2, fmaf(m2, kf, hvv));
            b3 = fminf(b3, fmaf(m3, kf, hvv));
            kf += 1.f;
        }
        const int sLo = max(0, ib - WIN);
        const int sHi = min(HW - 1, ib + WIN + 3);
        float bs[4] = {b0, b1, b2, b3};
        #pragma unroll
        for (int w = 0; w < 4; ++w) {
            const int i = ib + w;
            float D2 = (float)(i * i) + bs[w];
            // exactness: any excluded k has (i-k)^2 >= gap^2
            const int dl = i - sLo + 1, dr = sHi + 1 - i;
            const bool need = ((sLo > 0) && (D2 > (float)(dl * dl))) ||
                              ((sHi < HW - 1) && (D2 > (float)(dr * dr)));
            if (need) {  // statistically-dead exact fallback: full column scan
                float bb = 3e38f, k2 = 0.f;
                const float mm = -2.f * (float)i;
                for (int k = 0; k < HW; ++k) {
                    bb = fminf(bb, fmaf(mm, k2, hg[k * HW + j0 + jj]));
                    k2 += 1.f;
                }
                D2 = (float)(i * i) + bb;
            }
            const float wgt = (float)es[(i - i0) * 16 + jj];
            lsum = fmaf(wgt, sqrtf(D2), lsum);
        }
    }

    // reduce: wave shuffle then cross-wave via LDS; ONE plain store per block
    #pragma unroll
    for (int off = 32; off > 0; off >>= 1) lsum += __shfl_down(lsum, off);
    if ((threadIdx.x & 63) == 0) wsum[threadIdx.x >> 6] = lsum;
    __syncthreads();
    if (threadIdx.x == 0) {
        const int bid = blockIdx.x + 64 * (blockIdx.y + 8 * blockIdx.z);
        partial[bid] = wsum[0] + wsum[1] + wsum[2] + wsum[3];
    }
}

// ---------------- Kernel C: reduce 1024 partials + sigmoid ----------------
__global__ __launch_bounds__(256)
void k_fin(const float* __restrict__ partial, float* __restrict__ out)
{
    const int t = threadIdx.x;
    float s = partial[t] + partial[t + 256] + partial[t + 512] + partial[t + 768];
    #pragma unroll
    for (int off = 32; off > 0; off >>= 1) s += __shfl_down(s, off);
    __shared__ float w[4];
    if ((t & 63) == 0) w[t >> 6] = s;
    __syncthreads();
    if (t == 0) {
        const float tot = w[0] + w[1] + w[2] + w[3];
        const float loss = tot * (1.f / (2.f * 1024.f * 1024.f));
        out[0] = 1.f / (1.f + expf(-loss));
    }
}

extern "C" void kernel_launch(void* const* d_in, const int* in_sizes, int n_in,
                              void* d_out, int out_size, void* d_ws, size_t ws_size,
                              hipStream_t stream)
{
    const float* preds   = (const float*)d_in[0];
    const float* targets = (const float*)d_in[1];
    float* out = (float*)d_out;

    char* ws = (char*)d_ws;
    float* hp = (float*)ws;                               // 4 MB
    float* ht = hp + HW * HW;                             // 4 MB
    unsigned char* ep = (unsigned char*)(ht + HW * HW);   // 1 MB
    unsigned char* et = ep + HW * HW;                     // 1 MB
    float* partial = (float*)(et + HW * HW);              // 4 KB

    dim3 gA(HW / 4, 2, 1);
    k_rows<<<gA, 256, 0, stream>>>(preds, targets, hp, ht, ep, et);

    dim3 gB(HW / 16, HW / RPB, 2);
    k_cols<<<gB, 256, 0, stream>>>(hp, ht, ep, et, partial);

    k_fin<<<1, 256, 0, stream>>>(partial, out);
}